// Round 2
// baseline (1029.893 us; speedup 1.0000x reference)
//
#include <hip/hip_runtime.h>
#include <hip/hip_bf16.h>
#include <cmath>

// ---------------------------------------------------------------------------
// FourierNet fused forward, MI355X / gfx950.
// Round 2: fix — NTK scale s_in must apply to the xy rank-2 epilogue term too
// (reference scales the FULL 514-wide dot by 1/sqrt(514); R1 left the xy part
// unscaled -> absmax 4.78). One-line change in the proj epilogue.
// ---------------------------------------------------------------------------

#define NSC   4
#define NFREQ 64
#define HID   256
#define NBLK  2
#define INF   514
#define KF    512            // fourier K (xy handled as rank-2 epilogue)
#define TM    64             // points per block
#define FSTR  520            // f tile row stride (elems): 1040B/row -> 4-dw bank shift
#define HSTR  264            // h/t tile row stride: 528B/row -> 4-dw bank shift
#define NTHR  256
#define SMEM_BYTES 70912

#define W1_BF_OFF (NSC * HID * KF)                       // 524288
#define W2_BF_OFF (W1_BF_OFF + NSC * NBLK * HID * HID)   // 1048576
#define WSB_ELEMS (W2_BF_OFF + NSC * NBLK * HID * HID)   // 1572864 bf16

static constexpr float S_IN = 0.04411042041035620f;  // 1/sqrt(514)
static constexpr float S_H  = 0.0625f;               // 1/sqrt(256)

typedef __attribute__((ext_vector_type(8))) short bf16x8;
typedef __attribute__((ext_vector_type(4))) float f32x4;

__device__ __forceinline__ unsigned short f2bf(float v) {
  __hip_bfloat16 b = __float2bfloat16(v);   // RNE
  unsigned short u;
  __builtin_memcpy(&u, &b, 2);
  return u;
}

__device__ __forceinline__ float geluf(float x) {
  return 0.5f * x * (1.0f + erff(x * 0.7071067811865476f));
}

// NT GEMM inner loop: C[64 x 64/wave] += A(lds bf16) * B(row-major weights)^T
// A frag: row = lane&15 (+16*rf), k = ks*32 + (lane>>4)*8 .. +7
// B frag: col = cbase+cf*16+(lane&15), same k slice
// C frag: col = lane&15, row = (lane>>4)*4 + reg   [m89-verified]
template<bool WS, int KSTEPS, int ASTRIDE>
__device__ __forceinline__ void gemm_nt(const unsigned short* a_lds,
                                        const unsigned short* __restrict__ bw_bf,
                                        const float* __restrict__ bw_f,
                                        const int bstride_f, const int boff_f,
                                        const int lane, const int cbase,
                                        f32x4 acc[4][4]) {
  const int ar = lane & 15;
  const int kg = (lane >> 4) << 3;
  for (int ks = 0; ks < KSTEPS; ++ks) {
    const int kof = ks * 32 + kg;
    bf16x8 a[4];
#pragma unroll
    for (int rf = 0; rf < 4; ++rf)
      a[rf] = *(const bf16x8*)(a_lds + (rf * 16 + ar) * ASTRIDE + kof);
#pragma unroll
    for (int cf = 0; cf < 4; ++cf) {
      const int col = cbase + cf * 16 + ar;
      bf16x8 b;
      if constexpr (WS) {
        b = *(const bf16x8*)(bw_bf + col * (KSTEPS * 32) + kof);
      } else {
        const float* wp = bw_f + col * bstride_f + boff_f + kof;
        float2 w0 = *(const float2*)(wp + 0);
        float2 w1 = *(const float2*)(wp + 2);
        float2 w2 = *(const float2*)(wp + 4);
        float2 w3 = *(const float2*)(wp + 6);
        b[0] = (short)f2bf(w0.x); b[1] = (short)f2bf(w0.y);
        b[2] = (short)f2bf(w1.x); b[3] = (short)f2bf(w1.y);
        b[4] = (short)f2bf(w2.x); b[5] = (short)f2bf(w2.y);
        b[6] = (short)f2bf(w3.x); b[7] = (short)f2bf(w3.y);
      }
#pragma unroll
      for (int rf = 0; rf < 4; ++rf)
        acc[rf][cf] = __builtin_amdgcn_mfma_f32_16x16x32_bf16(a[rf], b, acc[rf][cf], 0, 0, 0);
    }
  }
}

__global__ void cvt_weights(const float* __restrict__ projW,
                            const float* __restrict__ w1,
                            const float* __restrict__ w2,
                            unsigned short* __restrict__ o) {
  const int n1 = NSC * HID * KF;
  const int n2 = NSC * NBLK * HID * HID;
  const int tot = n1 + 2 * n2;
  for (int i = blockIdx.x * blockDim.x + threadIdx.x; i < tot;
       i += gridDim.x * blockDim.x) {
    float v;
    if (i < n1)           v = projW[(i >> 9) * INF + 2 + (i & 511)];
    else if (i < n1 + n2) v = w1[i - n1];
    else                  v = w2[i - n1 - n2];
    o[i] = f2bf(v);
  }
}

template<bool WS>
__global__ __launch_bounds__(NTHR, 2)
void fnet_fused(const float* __restrict__ xy,
                const float* __restrict__ w_x,
                const float* __restrict__ w_y,
                const float* __restrict__ proj_W,
                const float* __restrict__ proj_b,
                const float* __restrict__ blk_W1,
                const float* __restrict__ blk_b1,
                const float* __restrict__ blk_W2,
                const float* __restrict__ blk_b2,
                const float* __restrict__ head_W,
                const float* __restrict__ head_b,
                const float* __restrict__ sc_W,
                const unsigned short* __restrict__ wsb,
                float* __restrict__ out) {
  extern __shared__ char smem[];
  unsigned short* f_lds = (unsigned short*)smem;                 // 64x520 bf16 (fourier phase)
  unsigned short* h_lds = (unsigned short*)smem;                 // 64x264 bf16 (aliases f)
  unsigned short* t_lds = (unsigned short*)(smem + TM * HSTR * 2);
  float* xyx = (float*)(smem + 67584);
  float* xyy = xyx + TM;
  float* Bxy = xyy + TM;          // Bx[64] | By[64]
  float* scf = Bxy + 2 * NFREQ;   // 512 shortcut weights (fourier cols)
  float* outl = scf + KF;         // 64 output accumulators

  const int tid  = threadIdx.x;
  const int lane = tid & 63;
  const int wave = tid >> 6;
  const int m0   = blockIdx.x * TM;
  const int cbase = wave * 64;
  const int ar    = lane & 15;
  const int rbase = (lane >> 4) << 2;

  if (tid < TM) {
    xyx[tid] = xy[(m0 + tid) * 2];
    xyy[tid] = xy[(m0 + tid) * 2 + 1];
    outl[tid] = 0.f;
  }

  float hwv[4];
#pragma unroll
  for (int cf = 0; cf < 4; ++cf) hwv[cf] = head_W[cbase + cf * 16 + ar];

  const int fm = tid >> 2;   // fourier: point index
  const int fq = tid & 3;    // fourier: freq quarter
  float psc = 0.f;           // shortcut partial (this thread's (m, 16 freqs), all scales)

  for (int s = 0; s < NSC; ++s) {
    __syncthreads();
    // ---- stage exp(w) and shortcut slice ----
    if (tid < NFREQ)          Bxy[tid] = expf(w_x[s * NFREQ + tid]);
    else if (tid < 2 * NFREQ) Bxy[tid] = expf(w_y[s * NFREQ + tid - NFREQ]);
    scf[tid]       = sc_W[s * INF + 2 + tid];
    scf[tid + 256] = sc_W[s * INF + 2 + tid + 256];
    __syncthreads();

    // ---- fourier features -> f_lds (bf16), fused shortcut dot (fp32) ----
    {
      const float x = xyx[fm], y = xyy[fm];
      if (fq == 0) psc += x * sc_W[s * INF] + y * sc_W[s * INF + 1];
      for (int i = 0; i < 8; ++i) {
        const int j0 = fq * 16 + 2 * i;
        float v0[8], v1[8];
#pragma unroll
        for (int jj = 0; jj < 2; ++jj) {
          float* vv = jj ? v1 : v0;
          const float bx = Bxy[j0 + jj], by = Bxy[NFREQ + j0 + jj];
          // angle pi*x*B == 2*pi*t, t = 0.5*x*B revolutions; v_sin takes revolutions
          float tx = 0.5f * x * bx; tx -= floorf(tx);
          float ty = 0.5f * y * by; ty -= floorf(ty);
          const float sx = __builtin_amdgcn_sinf(tx);
          const float cx = __builtin_amdgcn_cosf(tx);
          const float sy = __builtin_amdgcn_sinf(ty);
          const float cy = __builtin_amdgcn_cosf(ty);
          const float p1 = sx * cy, p2 = cx * sy, p3 = cx * cy, p4 = sx * sy;
          vv[0] = sx; vv[1] = cx; vv[2] = sy; vv[3] = cy;
          vv[4] = p1 + p2; vv[5] = p3 - p4; vv[6] = p1 - p2; vv[7] = p3 + p4;
        }
        unsigned int* dst = (unsigned int*)(f_lds + fm * FSTR + j0);
#pragma unroll
        for (int g = 0; g < 8; ++g) {
          dst[g * 32] = (unsigned int)f2bf(v0[g]) | ((unsigned int)f2bf(v1[g]) << 16);
          const float2 s2 = *(const float2*)(scf + g * NFREQ + j0);
          psc += v0[g] * s2.x + v1[g] * s2.y;   // shortcut uses unrounded fp32 values
        }
      }
    }
    __syncthreads();

    // ---- proj GEMM: h = gelu((f@W^T + x*W[:,0] + y*W[:,1]) * s_in + b) ----
    f32x4 acc[4][4];
#pragma unroll
    for (int a_ = 0; a_ < 4; ++a_)
#pragma unroll
      for (int b_ = 0; b_ < 4; ++b_) acc[a_][b_] = (f32x4)0.f;

    gemm_nt<WS, 16, FSTR>(f_lds,
                          WS ? wsb + s * HID * KF : (const unsigned short*)nullptr,
                          proj_W + s * HID * INF, INF, 2, lane, cbase, acc);

    f32x4 hres[4][4];
#pragma unroll
    for (int cf = 0; cf < 4; ++cf) {
      const int col = cbase + cf * 16 + ar;
      const float pb  = proj_b[s * HID + col];
      const float wx0 = proj_W[(s * HID + col) * INF + 0];
      const float wy0 = proj_W[(s * HID + col) * INF + 1];
#pragma unroll
      for (int rf = 0; rf < 4; ++rf)
#pragma unroll
        for (int r = 0; r < 4; ++r) {
          const int row = rf * 16 + rbase + r;
          // R2 FIX: s_in scales the FULL 514-wide dot incl. the xy columns.
          hres[rf][cf][r] =
              geluf((acc[rf][cf][r] + xyx[row] * wx0 + xyy[row] * wy0) * S_IN + pb);
        }
    }
    __syncthreads();   // all waves done reading f_lds (h aliases it)
#pragma unroll
    for (int cf = 0; cf < 4; ++cf) {
      const int col = cbase + cf * 16 + ar;
#pragma unroll
      for (int rf = 0; rf < 4; ++rf)
#pragma unroll
        for (int r = 0; r < 4; ++r)
          h_lds[(rf * 16 + rbase + r) * HSTR + col] = f2bf(hres[rf][cf][r]);
    }
    __syncthreads();

    // ---- residual blocks ----
    for (int b = 0; b < NBLK; ++b) {
      const int wb = (s * NBLK + b) * HID;
      f32x4 acc2[4][4];
#pragma unroll
      for (int a_ = 0; a_ < 4; ++a_)
#pragma unroll
        for (int b_ = 0; b_ < 4; ++b_) acc2[a_][b_] = (f32x4)0.f;
      gemm_nt<WS, 8, HSTR>(h_lds,
                           WS ? wsb + W1_BF_OFF + wb * HID : (const unsigned short*)nullptr,
                           blk_W1 + wb * HID, HID, 0, lane, cbase, acc2);
      __syncthreads();   // everyone done reading h_lds and (prev iter) t_lds
#pragma unroll
      for (int cf = 0; cf < 4; ++cf) {
        const int col = cbase + cf * 16 + ar;
        const float b1v = blk_b1[wb + col];
#pragma unroll
        for (int rf = 0; rf < 4; ++rf)
#pragma unroll
          for (int r = 0; r < 4; ++r)
            t_lds[(rf * 16 + rbase + r) * HSTR + col] =
                f2bf(geluf(acc2[rf][cf][r] * S_H + b1v));
      }
      __syncthreads();
      f32x4 acc3[4][4];
#pragma unroll
      for (int a_ = 0; a_ < 4; ++a_)
#pragma unroll
        for (int b_ = 0; b_ < 4; ++b_) acc3[a_][b_] = (f32x4)0.f;
      gemm_nt<WS, 8, HSTR>(t_lds,
                           WS ? wsb + W2_BF_OFF + wb * HID : (const unsigned short*)nullptr,
                           blk_W2 + wb * HID, HID, 0, lane, cbase, acc3);
#pragma unroll
      for (int cf = 0; cf < 4; ++cf) {
        const int col = cbase + cf * 16 + ar;
        const float b2v = blk_b2[wb + col];
#pragma unroll
        for (int rf = 0; rf < 4; ++rf)
#pragma unroll
          for (int r = 0; r < 4; ++r)
            hres[rf][cf][r] += acc3[rf][cf][r] * S_H + b2v;
      }
      if (b + 1 < NBLK) {
        // safe: h_lds last read before the post-GEMM1 barrier; t readers untouched
#pragma unroll
        for (int cf = 0; cf < 4; ++cf) {
          const int col = cbase + cf * 16 + ar;
#pragma unroll
          for (int rf = 0; rf < 4; ++rf)
#pragma unroll
            for (int r = 0; r < 4; ++r)
              h_lds[(rf * 16 + rbase + r) * HSTR + col] = f2bf(hres[rf][cf][r]);
        }
      }
      __syncthreads();
    }

    // ---- head partial: out += h_s . head_W ----
#pragma unroll
    for (int rf = 0; rf < 4; ++rf)
#pragma unroll
      for (int r = 0; r < 4; ++r) {
        float v = hres[rf][0][r] * hwv[0] + hres[rf][1][r] * hwv[1]
                + hres[rf][2][r] * hwv[2] + hres[rf][3][r] * hwv[3];
        v += __shfl_xor(v, 1, 64);
        v += __shfl_xor(v, 2, 64);
        v += __shfl_xor(v, 4, 64);
        v += __shfl_xor(v, 8, 64);
        if (ar == 0) atomicAdd(&outl[rf * 16 + rbase + r], v);
      }
  }

  // ---- shortcut reduce (4 threads per point) + final write ----
  psc += __shfl_xor(psc, 1, 64);
  psc += __shfl_xor(psc, 2, 64);
  if (fq == 0) atomicAdd(&outl[fm], psc);
  __syncthreads();
  if (tid < TM) out[m0 + tid] = outl[tid] + head_b[0];
}

extern "C" void kernel_launch(void* const* d_in, const int* in_sizes, int n_in,
                              void* d_out, int out_size, void* d_ws, size_t ws_size,
                              hipStream_t stream) {
  (void)in_sizes; (void)n_in;
  const float* xy     = (const float*)d_in[0];
  const float* w_x    = (const float*)d_in[1];
  const float* w_y    = (const float*)d_in[2];
  const float* proj_W = (const float*)d_in[3];
  const float* proj_b = (const float*)d_in[4];
  const float* blk_W1 = (const float*)d_in[5];
  const float* blk_b1 = (const float*)d_in[6];
  const float* blk_W2 = (const float*)d_in[7];
  const float* blk_b2 = (const float*)d_in[8];
  const float* head_W = (const float*)d_in[9];
  const float* head_b = (const float*)d_in[10];
  const float* sc_W   = (const float*)d_in[11];
  float* out = (float*)d_out;

  const bool use_ws = ws_size >= (size_t)WSB_ELEMS * 2;
  const int nblocks = out_size / TM;   // 65536/64 = 1024

  if (use_ws) {
    hipFuncSetAttribute((const void*)fnet_fused<true>,
                        hipFuncAttributeMaxDynamicSharedMemorySize, SMEM_BYTES);
    cvt_weights<<<512, 256, 0, stream>>>(proj_W, blk_W1, blk_W2,
                                         (unsigned short*)d_ws);
    fnet_fused<true><<<nblocks, NTHR, SMEM_BYTES, stream>>>(
        xy, w_x, w_y, proj_W, proj_b, blk_W1, blk_b1, blk_W2, blk_b2,
        head_W, head_b, sc_W, (const unsigned short*)d_ws, out);
  } else {
    hipFuncSetAttribute((const void*)fnet_fused<false>,
                        hipFuncAttributeMaxDynamicSharedMemorySize, SMEM_BYTES);
    fnet_fused<false><<<nblocks, NTHR, SMEM_BYTES, stream>>>(
        xy, w_x, w_y, proj_W, proj_b, blk_W1, blk_b1, blk_W2, blk_b2,
        head_W, head_b, sc_W, (const unsigned short*)nullptr, out);
  }
}

// Round 3
// 783.396 us; speedup vs baseline: 1.3147x; 1.3147x over previous
//
#include <hip/hip_runtime.h>
#include <hip/hip_bf16.h>
#include <cmath>

// ---------------------------------------------------------------------------
// FourierNet fused forward, MI355X / gfx950.
// Round 3: latency attack. 512 thr / 8 waves per 64-point tile (4 waves/SIMD),
// swapped-operand MFMA (D: lane = 1 point x 4 consecutive H) so epilogues use
// packed ds_write_b64, explicit weight prefetch in the unrolled K loop.
// ---------------------------------------------------------------------------

#define NSC   4
#define NFREQ 64
#define HID   256
#define NBLK  2
#define INF   514
#define KF    512            // fourier K (xy handled as rank-2 epilogue)
#define TM    64             // points per block
#define FSTR  520            // f tile row stride (elems): 1040B/row
#define HSTR  264            // h/t tile row stride: 528B/row
#define NTHR  512
#define SMEM_BYTES 70912

#define W1_BF_OFF (NSC * HID * KF)                       // 524288
#define W2_BF_OFF (W1_BF_OFF + NSC * NBLK * HID * HID)   // 1048576
#define WSB_ELEMS (W2_BF_OFF + NSC * NBLK * HID * HID)   // 1572864 bf16

static constexpr float S_IN = 0.04411042041035620f;  // 1/sqrt(514)
static constexpr float S_H  = 0.0625f;               // 1/sqrt(256)

typedef __attribute__((ext_vector_type(8))) short bf16x8;
typedef __attribute__((ext_vector_type(4))) float f32x4;

__device__ __forceinline__ unsigned short f2bf(float v) {
  __hip_bfloat16 b = __float2bfloat16(v);   // RNE
  unsigned short u;
  __builtin_memcpy(&u, &b, 2);
  return u;
}

__device__ __forceinline__ uint2 pack4(float a, float b, float c, float d) {
  return make_uint2((unsigned)f2bf(a) | ((unsigned)f2bf(b) << 16),
                    (unsigned)f2bf(c) | ((unsigned)f2bf(d) << 16));
}

__device__ __forceinline__ float geluf(float x) {
  return 0.5f * x * (1.0f + erff(x * 0.7071067811865476f));
}

// Swapped-operand NT GEMM: acc[hf][pf] = W * F^T fragment-wise.
//   W (1st operand): row = hbase+hf*16+(lane&15) of weight matrix [H][K] row-major
//   F (2nd operand, LDS): point = pf*16+(lane&15), k-contiguous
//   D: col(=point within 16-group) = lane&15, row(=H) = (lane>>4)*4+reg  [m89]
// Weight frag for ks+1 is prefetched before the MFMAs of ks.
template<bool WS, int KSTEPS, int ASTRIDE>
__device__ __forceinline__ void gemm_wn(const unsigned short* a_lds,
                                        const unsigned short* __restrict__ w_bf,
                                        const float* __restrict__ w_f,
                                        const int wstride_f, const int woff_f,
                                        const int lane, const int hbase,
                                        f32x4 acc[2][4]) {
  const int ar = lane & 15;
  const int kg = (lane >> 4) << 3;
  constexpr int K = KSTEPS * 32;

  bf16x8 wcur[2], wnxt[2];

  auto loadw = [&](int ks, bf16x8 w[2]) {
    const int kof = ks * 32 + kg;
#pragma unroll
    for (int hf = 0; hf < 2; ++hf) {
      const int row = hbase + hf * 16 + ar;
      if constexpr (WS) {
        w[hf] = *(const bf16x8*)(w_bf + row * K + kof);
      } else {
        const float* wp = w_f + row * wstride_f + woff_f + kof;
        float2 w0 = *(const float2*)(wp + 0);
        float2 w1 = *(const float2*)(wp + 2);
        float2 w2 = *(const float2*)(wp + 4);
        float2 w3 = *(const float2*)(wp + 6);
        w[hf][0] = (short)f2bf(w0.x); w[hf][1] = (short)f2bf(w0.y);
        w[hf][2] = (short)f2bf(w1.x); w[hf][3] = (short)f2bf(w1.y);
        w[hf][4] = (short)f2bf(w2.x); w[hf][5] = (short)f2bf(w2.y);
        w[hf][6] = (short)f2bf(w3.x); w[hf][7] = (short)f2bf(w3.y);
      }
    }
  };

  loadw(0, wcur);
#pragma unroll
  for (int ks = 0; ks < KSTEPS; ++ks) {
    if (ks + 1 < KSTEPS) loadw(ks + 1, wnxt);
    const int kof = ks * 32 + kg;
    bf16x8 a[4];
#pragma unroll
    for (int pf = 0; pf < 4; ++pf)
      a[pf] = *(const bf16x8*)(a_lds + (pf * 16 + ar) * ASTRIDE + kof);
#pragma unroll
    for (int hf = 0; hf < 2; ++hf)
#pragma unroll
      for (int pf = 0; pf < 4; ++pf)
        acc[hf][pf] = __builtin_amdgcn_mfma_f32_16x16x32_bf16(wcur[hf], a[pf],
                                                              acc[hf][pf], 0, 0, 0);
    wcur[0] = wnxt[0];
    wcur[1] = wnxt[1];
  }
}

__global__ void cvt_weights(const float* __restrict__ projW,
                            const float* __restrict__ w1,
                            const float* __restrict__ w2,
                            unsigned short* __restrict__ o) {
  const int n1 = NSC * HID * KF;
  const int n2 = NSC * NBLK * HID * HID;
  const int tot = n1 + 2 * n2;
  for (int i = blockIdx.x * blockDim.x + threadIdx.x; i < tot;
       i += gridDim.x * blockDim.x) {
    float v;
    if (i < n1)           v = projW[(i >> 9) * INF + 2 + (i & 511)];
    else if (i < n1 + n2) v = w1[i - n1];
    else                  v = w2[i - n1 - n2];
    o[i] = f2bf(v);
  }
}

template<bool WS>
__global__ __launch_bounds__(NTHR, 4)
void fnet_fused(const float* __restrict__ xy,
                const float* __restrict__ w_x,
                const float* __restrict__ w_y,
                const float* __restrict__ proj_W,
                const float* __restrict__ proj_b,
                const float* __restrict__ blk_W1,
                const float* __restrict__ blk_b1,
                const float* __restrict__ blk_W2,
                const float* __restrict__ blk_b2,
                const float* __restrict__ head_W,
                const float* __restrict__ head_b,
                const float* __restrict__ sc_W,
                const unsigned short* __restrict__ wsb,
                float* __restrict__ out) {
  extern __shared__ char smem[];
  unsigned short* f_lds = (unsigned short*)smem;                 // 64x520 bf16
  unsigned short* h_lds = (unsigned short*)smem;                 // 64x264 (aliases f lower)
  unsigned short* t_lds = (unsigned short*)(smem + TM * HSTR * 2); // aliases f upper
  float* xyx = (float*)(smem + 67584);
  float* xyy = xyx + TM;
  float* Bxy = xyy + TM;          // Bx[64] | By[64]
  float* scf = Bxy + 2 * NFREQ;   // 512 shortcut weights (fourier cols)
  float* outl = scf + KF;         // 64 output accumulators

  const int tid  = threadIdx.x;
  const int lane = tid & 63;
  const int wave = tid >> 6;           // 0..7
  const int m0   = blockIdx.x * TM;
  const int hbase = wave * 32;         // this wave's 32 H-columns
  const int ar    = lane & 15;         // point-within-group / weight-row lane
  const int g     = lane >> 4;         // H sub-block (4 consecutive H per reg quad)

  if (tid < TM) {
    xyx[tid] = xy[(m0 + tid) * 2];
    xyy[tid] = xy[(m0 + tid) * 2 + 1];
    outl[tid] = 0.f;
  }

  // head weights for this lane's 8 H slots
  float hw[2][4];
#pragma unroll
  for (int hf = 0; hf < 2; ++hf) {
    float4 h4 = *(const float4*)(head_W + hbase + hf * 16 + 4 * g);
    hw[hf][0] = h4.x; hw[hf][1] = h4.y; hw[hf][2] = h4.z; hw[hf][3] = h4.w;
  }

  const int fm = tid >> 3;   // fourier: point index (0..63)
  const int fq = tid & 7;    // fourier: freq octant (8 freqs each)
  float psc = 0.f;           // shortcut partial

  for (int s = 0; s < NSC; ++s) {
    __syncthreads();   // prev scale's LDS reads complete before restage
    if (tid < NFREQ)          Bxy[tid] = expf(w_x[s * NFREQ + tid]);
    else if (tid < 2 * NFREQ) Bxy[tid] = expf(w_y[s * NFREQ + tid - NFREQ]);
    scf[tid] = sc_W[s * INF + 2 + tid];
    __syncthreads();

    // ---- fourier features -> f_lds (bf16, b64 packed), fused shortcut dot ----
    {
      const float x = xyx[fm], y = xyy[fm];
      if (fq == 0) psc += x * sc_W[s * INF] + y * sc_W[s * INF + 1];
#pragma unroll
      for (int i = 0; i < 2; ++i) {
        const int j0 = fq * 8 + i * 4;
        float ft[8][4];
#pragma unroll
        for (int jj = 0; jj < 4; ++jj) {
          const float bx = Bxy[j0 + jj], by = Bxy[NFREQ + j0 + jj];
          // angle pi*x*B == 2*pi*t revolutions; v_sin/v_cos take revolutions
          float tx = 0.5f * x * bx; tx -= floorf(tx);
          float ty = 0.5f * y * by; ty -= floorf(ty);
          const float sx = __builtin_amdgcn_sinf(tx);
          const float cx = __builtin_amdgcn_cosf(tx);
          const float sy = __builtin_amdgcn_sinf(ty);
          const float cy = __builtin_amdgcn_cosf(ty);
          const float p1 = sx * cy, p2 = cx * sy, p3 = cx * cy, p4 = sx * sy;
          ft[0][jj] = sx;      ft[1][jj] = cx;
          ft[2][jj] = sy;      ft[3][jj] = cy;
          ft[4][jj] = p1 + p2; ft[5][jj] = p3 - p4;
          ft[6][jj] = p1 - p2; ft[7][jj] = p3 + p4;
        }
#pragma unroll
        for (int gr = 0; gr < 8; ++gr) {
          *(uint2*)((char*)smem + fm * (FSTR * 2) + gr * 128 + j0 * 2) =
              pack4(ft[gr][0], ft[gr][1], ft[gr][2], ft[gr][3]);
          const float4 s4 = *(const float4*)(scf + gr * NFREQ + j0);
          psc += ft[gr][0] * s4.x + ft[gr][1] * s4.y
               + ft[gr][2] * s4.z + ft[gr][3] * s4.w;
        }
      }
    }
    __syncthreads();

    // ---- proj GEMM: h = gelu((f@W^T + x*W[:,0] + y*W[:,1]) * s_in + b) ----
    f32x4 acc[2][4];
#pragma unroll
    for (int a_ = 0; a_ < 2; ++a_)
#pragma unroll
      for (int b_ = 0; b_ < 4; ++b_) acc[a_][b_] = (f32x4)0.f;

    gemm_wn<WS, 16, FSTR>(f_lds,
                          WS ? wsb + s * HID * KF : (const unsigned short*)nullptr,
                          proj_W + s * HID * INF, INF, 2, lane, hbase, acc);

    // epilogue: per lane, 4 points (pf) x 8 H (hf,r)
    float xp[4], yp[4];
#pragma unroll
    for (int pf = 0; pf < 4; ++pf) { xp[pf] = xyx[pf * 16 + ar]; yp[pf] = xyy[pf * 16 + ar]; }

    f32x4 hres[2][4];
#pragma unroll
    for (int hf = 0; hf < 2; ++hf) {
      const int Hb = hbase + hf * 16 + 4 * g;
      const float4 pb4 = *(const float4*)(proj_b + s * HID + Hb);
      float wx0[4], wy0[4], pbv[4] = {pb4.x, pb4.y, pb4.z, pb4.w};
#pragma unroll
      for (int r = 0; r < 4; ++r) {
        const float2 w01 = *(const float2*)(proj_W + (size_t)(s * HID + Hb + r) * INF);
        wx0[r] = w01.x; wy0[r] = w01.y;
      }
#pragma unroll
      for (int pf = 0; pf < 4; ++pf)
#pragma unroll
        for (int r = 0; r < 4; ++r)
          hres[hf][pf][r] = geluf((acc[hf][pf][r] + xp[pf] * wx0[r] + yp[pf] * wy0[r])
                                      * S_IN + pbv[r]);
    }
    __syncthreads();   // all waves done reading f_lds (h aliases it)
#pragma unroll
    for (int hf = 0; hf < 2; ++hf) {
      const int Hb = hbase + hf * 16 + 4 * g;
#pragma unroll
      for (int pf = 0; pf < 4; ++pf)
        *(uint2*)(h_lds + (pf * 16 + ar) * HSTR + Hb) =
            pack4(hres[hf][pf][0], hres[hf][pf][1], hres[hf][pf][2], hres[hf][pf][3]);
    }
    __syncthreads();

    // ---- residual blocks ----
    for (int b = 0; b < NBLK; ++b) {
      const int wb = (s * NBLK + b) * HID;
      f32x4 acc2[2][4];
#pragma unroll
      for (int a_ = 0; a_ < 2; ++a_)
#pragma unroll
        for (int b_ = 0; b_ < 4; ++b_) acc2[a_][b_] = (f32x4)0.f;
      gemm_wn<WS, 8, HSTR>(h_lds,
                           WS ? wsb + W1_BF_OFF + wb * HID : (const unsigned short*)nullptr,
                           blk_W1 + wb * HID, HID, 0, lane, hbase, acc2);
      // t-store: t != h, and prev-iter t readers all passed last barrier
#pragma unroll
      for (int hf = 0; hf < 2; ++hf) {
        const int Hb = hbase + hf * 16 + 4 * g;
        const float4 b14 = *(const float4*)(blk_b1 + wb + Hb);
        const float b1v[4] = {b14.x, b14.y, b14.z, b14.w};
#pragma unroll
        for (int pf = 0; pf < 4; ++pf)
          *(uint2*)(t_lds + (pf * 16 + ar) * HSTR + Hb) =
              pack4(geluf(acc2[hf][pf][0] * S_H + b1v[0]),
                    geluf(acc2[hf][pf][1] * S_H + b1v[1]),
                    geluf(acc2[hf][pf][2] * S_H + b1v[2]),
                    geluf(acc2[hf][pf][3] * S_H + b1v[3]));
      }
      __syncthreads();   // t complete (and all h reads done) before gemm2
      f32x4 acc3[2][4];
#pragma unroll
      for (int a_ = 0; a_ < 2; ++a_)
#pragma unroll
        for (int b_ = 0; b_ < 4; ++b_) acc3[a_][b_] = (f32x4)0.f;
      gemm_wn<WS, 8, HSTR>(t_lds,
                           WS ? wsb + W2_BF_OFF + wb * HID : (const unsigned short*)nullptr,
                           blk_W2 + wb * HID, HID, 0, lane, hbase, acc3);
#pragma unroll
      for (int hf = 0; hf < 2; ++hf) {
        const int Hb = hbase + hf * 16 + 4 * g;
        const float4 b24 = *(const float4*)(blk_b2 + wb + Hb);
        const float b2v[4] = {b24.x, b24.y, b24.z, b24.w};
#pragma unroll
        for (int pf = 0; pf < 4; ++pf)
#pragma unroll
          for (int r = 0; r < 4; ++r)
            hres[hf][pf][r] += acc3[hf][pf][r] * S_H + b2v[r];
      }
      if (b + 1 < NBLK) {
        // all waves passed pre-gemm2 barrier => h reads done; t readers unaffected
#pragma unroll
        for (int hf = 0; hf < 2; ++hf) {
          const int Hb = hbase + hf * 16 + 4 * g;
#pragma unroll
          for (int pf = 0; pf < 4; ++pf)
            *(uint2*)(h_lds + (pf * 16 + ar) * HSTR + Hb) =
                pack4(hres[hf][pf][0], hres[hf][pf][1], hres[hf][pf][2], hres[hf][pf][3]);
        }
      }
      __syncthreads();
    }

    // ---- head partial: outl[point] += sum_H h[point][H]*head_W[H] ----
#pragma unroll
    for (int pf = 0; pf < 4; ++pf) {
      float v = 0.f;
#pragma unroll
      for (int hf = 0; hf < 2; ++hf)
#pragma unroll
        for (int r = 0; r < 4; ++r) v += hres[hf][pf][r] * hw[hf][r];
      v += __shfl_xor(v, 16, 64);
      v += __shfl_xor(v, 32, 64);
      if (lane < 16) atomicAdd(&outl[pf * 16 + ar], v);
    }
  }

  // ---- shortcut reduce (8 threads per point) + final write ----
  psc += __shfl_xor(psc, 1, 64);
  psc += __shfl_xor(psc, 2, 64);
  psc += __shfl_xor(psc, 4, 64);
  if (fq == 0) atomicAdd(&outl[fm], psc);
  __syncthreads();
  if (tid < TM) out[m0 + tid] = outl[tid] + head_b[0];
}

extern "C" void kernel_launch(void* const* d_in, const int* in_sizes, int n_in,
                              void* d_out, int out_size, void* d_ws, size_t ws_size,
                              hipStream_t stream) {
  (void)in_sizes; (void)n_in;
  const float* xy     = (const float*)d_in[0];
  const float* w_x    = (const float*)d_in[1];
  const float* w_y    = (const float*)d_in[2];
  const float* proj_W = (const float*)d_in[3];
  const float* proj_b = (const float*)d_in[4];
  const float* blk_W1 = (const float*)d_in[5];
  const float* blk_b1 = (const float*)d_in[6];
  const float* blk_W2 = (const float*)d_in[7];
  const float* blk_b2 = (const float*)d_in[8];
  const float* head_W = (const float*)d_in[9];
  const float* head_b = (const float*)d_in[10];
  const float* sc_W   = (const float*)d_in[11];
  float* out = (float*)d_out;

  const bool use_ws = ws_size >= (size_t)WSB_ELEMS * 2;
  const int nblocks = out_size / TM;   // 65536/64 = 1024

  if (use_ws) {
    hipFuncSetAttribute((const void*)fnet_fused<true>,
                        hipFuncAttributeMaxDynamicSharedMemorySize, SMEM_BYTES);
    cvt_weights<<<512, 256, 0, stream>>>(proj_W, blk_W1, blk_W2,
                                         (unsigned short*)d_ws);
    fnet_fused<true><<<nblocks, NTHR, SMEM_BYTES, stream>>>(
        xy, w_x, w_y, proj_W, proj_b, blk_W1, blk_b1, blk_W2, blk_b2,
        head_W, head_b, sc_W, (const unsigned short*)d_ws, out);
  } else {
    hipFuncSetAttribute((const void*)fnet_fused<false>,
                        hipFuncAttributeMaxDynamicSharedMemorySize, SMEM_BYTES);
    fnet_fused<false><<<nblocks, NTHR, SMEM_BYTES, stream>>>(
        xy, w_x, w_y, proj_W, proj_b, blk_W1, blk_b1, blk_W2, blk_b2,
        head_W, head_b, sc_W, (const unsigned short*)nullptr, out);
  }
}